// Round 1
// baseline (626.911 us; speedup 1.0000x reference)
//
#include <hip/hip_runtime.h>
#include <stdint.h>

#define PHM      4
#define IN_FEATS 2048
#define OUT_FEATS 8192
#define TOKENS   8192
#define IN_PER   512    // IN_FEATS / PHM
#define OUT_PER  2048   // OUT_FEATS / PHM

typedef __attribute__((ext_vector_type(8))) short short8;
typedef __attribute__((ext_vector_type(4))) float f32x4;
typedef __attribute__((ext_vector_type(8))) unsigned short u16x8;

// round-to-nearest-even fp32 -> bf16 (inputs are finite Gaussians, no NaN path)
__device__ inline unsigned short f2bf(float f) {
    unsigned int u = __builtin_bit_cast(unsigned int, f);
    u += 0x7fffu + ((u >> 16) & 1u);
    return (unsigned short)(u >> 16);
}

// ---------------- kernel 1: x fp32 -> bf16, 8 elem/thread ----------------
__global__ void cvt_x_kernel(const float* __restrict__ x,
                             unsigned short* __restrict__ xb) {
    int i = blockIdx.x * blockDim.x + threadIdx.x;  // one per 8 elements
    const float4* x4 = (const float4*)x;
    float4 v0 = x4[2 * i];
    float4 v1 = x4[2 * i + 1];
    u16x8 o;
    o[0] = f2bf(v0.x); o[1] = f2bf(v0.y); o[2] = f2bf(v0.z); o[3] = f2bf(v0.w);
    o[4] = f2bf(v1.x); o[5] = f2bf(v1.y); o[6] = f2bf(v1.z); o[7] = f2bf(v1.w);
    *(u16x8*)(xb + 8 * (size_t)i) = o;
}

// ---------------- kernel 2: build Ht[n][k] = sum_i rule[i,a,kq]*W[i,c,p] ----
// n = kq*OUT_PER + p, k = a*IN_PER + c.  Block = (32 c) x (64 p) tile, LDS
// transpose so W reads are coalesced + each W element read exactly once.
__global__ void build_ht_kernel(const float* __restrict__ rule,  // [4][4][4] (i,a,kq)
                                const float* __restrict__ W,     // [4][512][2048]
                                unsigned short* __restrict__ Ht) // [8192][2048] bf16
{
    __shared__ float lds[PHM][32][65];  // +1 pad: conflict-free column reads
    const int tid = threadIdx.x;
    const int c0 = blockIdx.x * 32;
    const int p0 = blockIdx.y * 64;

    // stage W[i][c0+cc][p0+pp], pp fastest -> fully coalesced
    #pragma unroll
    for (int it = 0; it < 32; ++it) {
        int idx = it * 256 + tid;        // 0..8191
        int pp = idx & 63;
        int cc = (idx >> 6) & 31;
        int i  = idx >> 11;
        lds[i][cc][pp] = W[((size_t)(i * IN_PER + c0 + cc)) * OUT_PER + p0 + pp];
    }
    __syncthreads();

    const int pp = tid >> 2;         // 0..63
    const int j0 = (tid & 3) * 8;    // c-chunk of 8
    float w[PHM][8];
    #pragma unroll
    for (int i = 0; i < PHM; ++i)
        #pragma unroll
        for (int j = 0; j < 8; ++j)
            w[i][j] = lds[i][j0 + j][pp];

    #pragma unroll
    for (int a = 0; a < PHM; ++a) {
        #pragma unroll
        for (int kq = 0; kq < PHM; ++kq) {
            float r0 = rule[(0 * PHM + a) * PHM + kq];
            float r1 = rule[(1 * PHM + a) * PHM + kq];
            float r2 = rule[(2 * PHM + a) * PHM + kq];
            float r3 = rule[(3 * PHM + a) * PHM + kq];
            u16x8 o;
            #pragma unroll
            for (int j = 0; j < 8; ++j) {
                float v = r0 * w[0][j] + r1 * w[1][j] + r2 * w[2][j] + r3 * w[3][j];
                o[j] = f2bf(v);
            }
            size_t n = (size_t)(kq * OUT_PER + p0 + pp);
            *(u16x8*)(Ht + n * IN_FEATS + a * IN_PER + c0 + j0) = o;  // 16B coalesced
        }
    }
}

// ---------------- kernel 3: C[M][N] = A[M][K] * B[N][K]^T + bias ------------
// m97-ladder structure: 128x128 tile, BK=32, 4 waves x 4x4 MFMA 16x16x32 bf16,
// global_load_lds width-16 staging, ds_read_b128 fragments.
#define BM 128
#define BN 128
#define BK 32

__device__ inline void load_lds16(const unsigned short* g, unsigned short* l) {
    __builtin_amdgcn_global_load_lds(
        (const __attribute__((address_space(1))) unsigned int*)g,
        (__attribute__((address_space(3))) unsigned int*)l,
        16, 0, 0);
}

__global__ __launch_bounds__(256) void gemm_bt_kernel(
    const unsigned short* __restrict__ A,   // [M][K] bf16 (x)
    const unsigned short* __restrict__ B,   // [N][K] bf16 (Ht)
    const float* __restrict__ bias,         // [N]
    float* __restrict__ C)                  // [M][N] fp32
{
    constexpr int N = OUT_FEATS, K = IN_FEATS;
    __shared__ unsigned short As[BM * BK];  // [row][k], 64B rows, 8 KB
    __shared__ unsigned short Bs[BN * BK];  // [n][k], 8 KB

    const int tid  = threadIdx.x;
    const int wave = tid >> 6;
    const int lane = tid & 63;
    const int bn = blockIdx.x;
    const int bm = blockIdx.y;

    const int wm = (wave >> 1) * 64;        // wave's C sub-tile
    const int wn = (wave & 1) * 64;

    // staging lane map: lane l -> row l/4, k-chunk (l%4)*8 (matches HW
    // wave-uniform-base + lane*16B LDS scatter of global_load_lds)
    const int s_row = lane >> 2;
    const int s_col = (lane & 3) * 8;

    const unsigned short* Ag = A + ((size_t)(bm * BM + wave * 32 + s_row)) * K + s_col;
    const unsigned short* Bg = B + ((size_t)(bn * BN + wave * 32 + s_row)) * K + s_col;
    unsigned short* As_w = &As[(wave * 32) * BK];   // wave-uniform LDS base
    unsigned short* Bs_w = &Bs[(wave * 32) * BK];

    const int fm = lane & 15;               // fragment row (A) / col (B)
    const int fk = (lane >> 4) * 8;         // fragment k offset

    f32x4 acc[4][4] = {};

    for (int k0 = 0; k0 < K; k0 += BK) {
        __syncthreads();                    // prev iter done reading LDS
        load_lds16(Ag + k0,          As_w);
        load_lds16(Ag + 16 * K + k0, As_w + 16 * BK);
        load_lds16(Bg + k0,          Bs_w);
        load_lds16(Bg + 16 * K + k0, Bs_w + 16 * BK);
        __syncthreads();                    // drains vmcnt(0) -> tiles ready

        short8 af[4], bf[4];
        #pragma unroll
        for (int t = 0; t < 4; ++t)
            af[t] = *(const short8*)&As[(wm + t * 16 + fm) * BK + fk];
        #pragma unroll
        for (int t = 0; t < 4; ++t)
            bf[t] = *(const short8*)&Bs[(wn + t * 16 + fm) * BK + fk];
        #pragma unroll
        for (int i = 0; i < 4; ++i)
            #pragma unroll
            for (int j = 0; j < 4; ++j)
                acc[i][j] = __builtin_amdgcn_mfma_f32_16x16x32_bf16(
                    af[i], bf[j], acc[i][j], 0, 0, 0);
    }

    // epilogue: D row=(lane>>4)*4+r, col=lane&15 (verified m89/m91 mapping)
    const int cm = (lane >> 4) * 4;
    const int cn = lane & 15;
    #pragma unroll
    for (int j = 0; j < 4; ++j) {
        int col = bn * BN + wn + j * 16 + cn;
        float bv = bias[col];
        #pragma unroll
        for (int i = 0; i < 4; ++i) {
            int row0 = bm * BM + wm + i * 16 + cm;
            #pragma unroll
            for (int r = 0; r < 4; ++r)
                C[(size_t)(row0 + r) * N + col] = acc[i][j][r] + bv;
        }
    }
}

extern "C" void kernel_launch(void* const* d_in, const int* in_sizes, int n_in,
                              void* d_out, int out_size, void* d_ws, size_t ws_size,
                              hipStream_t stream) {
    const float* x    = (const float*)d_in[0];   // [8192][2048]
    const float* rule = (const float*)d_in[1];   // [4][4][4]
    const float* W    = (const float*)d_in[2];   // [4][512][2048]
    const float* b    = (const float*)d_in[3];   // [8192]
    float* y = (float*)d_out;                    // [8192][8192]

    unsigned short* xb = (unsigned short*)d_ws;                       // 32 MB
    unsigned short* Ht = (unsigned short*)((char*)d_ws +
                         (size_t)TOKENS * IN_FEATS * sizeof(unsigned short)); // 32 MB

    // 1) x -> bf16
    cvt_x_kernel<<<(TOKENS * IN_FEATS) / 8 / 256, 256, 0, stream>>>(x, xb);
    // 2) Ht (B^T, k-contiguous) in bf16
    build_ht_kernel<<<dim3(IN_PER / 32, OUT_PER / 64), 256, 0, stream>>>(rule, W, Ht);
    // 3) big GEMM
    gemm_bt_kernel<<<dim3(OUT_FEATS / BN, TOKENS / BM), 256, 0, stream>>>(xb, Ht, b, y);
}

// Round 3
// 614.032 us; speedup vs baseline: 1.0210x; 1.0210x over previous
//
#include <hip/hip_runtime.h>
#include <stdint.h>

#define PHM      4
#define IN_FEATS 2048
#define OUT_FEATS 8192
#define TOKENS   8192
#define IN_PER   512    // IN_FEATS / PHM
#define OUT_PER  2048   // OUT_FEATS / PHM

typedef __attribute__((ext_vector_type(8)))  short short8;
typedef __attribute__((ext_vector_type(16))) float f32x16;
typedef __attribute__((ext_vector_type(8)))  unsigned short u16x8;

// round-to-nearest-even fp32 -> bf16 (inputs are finite Gaussians, no NaN path)
__device__ inline unsigned short f2bf(float f) {
    unsigned int u = __builtin_bit_cast(unsigned int, f);
    u += 0x7fffu + ((u >> 16) & 1u);
    return (unsigned short)(u >> 16);
}

// ---------------- kernel 1: x fp32 -> bf16, 8 elem/thread ----------------
__global__ void cvt_x_kernel(const float* __restrict__ x,
                             unsigned short* __restrict__ xb) {
    int i = blockIdx.x * blockDim.x + threadIdx.x;  // one per 8 elements
    const float4* x4 = (const float4*)x;
    float4 v0 = x4[2 * i];
    float4 v1 = x4[2 * i + 1];
    u16x8 o;
    o[0] = f2bf(v0.x); o[1] = f2bf(v0.y); o[2] = f2bf(v0.z); o[3] = f2bf(v0.w);
    o[4] = f2bf(v1.x); o[5] = f2bf(v1.y); o[6] = f2bf(v1.z); o[7] = f2bf(v1.w);
    *(u16x8*)(xb + 8 * (size_t)i) = o;
}

// ---------------- kernel 2: build Ht[n][k] = sum_i rule[i,a,kq]*W[i,c,p] ----
// n = kq*OUT_PER + p, k = a*IN_PER + c.  Block = (32 c) x (64 p) tile, LDS
// transpose so W reads are coalesced + each W element read exactly once.
__global__ void build_ht_kernel(const float* __restrict__ rule,  // [4][4][4] (i,a,kq)
                                const float* __restrict__ W,     // [4][512][2048]
                                unsigned short* __restrict__ Ht) // [8192][2048] bf16
{
    __shared__ float lds[PHM][32][65];  // +1 pad: conflict-free column reads
    const int tid = threadIdx.x;
    const int c0 = blockIdx.x * 32;
    const int p0 = blockIdx.y * 64;

    #pragma unroll
    for (int it = 0; it < 32; ++it) {
        int idx = it * 256 + tid;        // 0..8191
        int pp = idx & 63;
        int cc = (idx >> 6) & 31;
        int i  = idx >> 11;
        lds[i][cc][pp] = W[((size_t)(i * IN_PER + c0 + cc)) * OUT_PER + p0 + pp];
    }
    __syncthreads();

    const int pp = tid >> 2;         // 0..63
    const int j0 = (tid & 3) * 8;    // c-chunk of 8
    float w[PHM][8];
    #pragma unroll
    for (int i = 0; i < PHM; ++i)
        #pragma unroll
        for (int j = 0; j < 8; ++j)
            w[i][j] = lds[i][j0 + j][pp];

    #pragma unroll
    for (int a = 0; a < PHM; ++a) {
        #pragma unroll
        for (int kq = 0; kq < PHM; ++kq) {
            float r0 = rule[(0 * PHM + a) * PHM + kq];
            float r1 = rule[(1 * PHM + a) * PHM + kq];
            float r2 = rule[(2 * PHM + a) * PHM + kq];
            float r3 = rule[(3 * PHM + a) * PHM + kq];
            u16x8 o;
            #pragma unroll
            for (int j = 0; j < 8; ++j) {
                float v = r0 * w[0][j] + r1 * w[1][j] + r2 * w[2][j] + r3 * w[3][j];
                o[j] = f2bf(v);
            }
            size_t n = (size_t)(kq * OUT_PER + p0 + pp);
            *(u16x8*)(Ht + n * IN_FEATS + a * IN_PER + c0 + j0) = o;  // 16B coalesced
        }
    }
}

// ---------------- kernel 3: C[M][N] = A[M][K] * B[N][K]^T + bias ------------
// Round-3: 128x256 block, 4 waves (2x2), wave tile 64x128 as 2x4 of
// mfma_f32_32x32x16_bf16. Linear (unswizzled) LDS layout — isolating the
// round-2 post-timing race by removing the swizzle; explicit s_waitcnt(0)
// before the post-load barrier as a drain safety belt.
#define BM 128
#define BN 256
#define BK 32

__device__ inline void load_lds16(const unsigned short* g, unsigned short* l) {
    __builtin_amdgcn_global_load_lds(
        (const __attribute__((address_space(1))) unsigned int*)g,
        (__attribute__((address_space(3))) unsigned int*)l,
        16, 0, 0);
}

__global__ __launch_bounds__(256, 2) void gemm_bt_kernel(
    const unsigned short* __restrict__ A,   // [M][K] bf16 (x)
    const unsigned short* __restrict__ B,   // [N][K] bf16 (Ht)
    const float* __restrict__ bias,         // [N]
    float* __restrict__ C)                  // [M][N] fp32
{
    constexpr int N = OUT_FEATS, K = IN_FEATS;
    __shared__ unsigned short As[BM * BK];  // [row][k] 64B rows, 8 KB
    __shared__ unsigned short Bs[BN * BK];  // [n][k]   64B rows, 16 KB

    const int tid  = threadIdx.x;
    const int wave = tid >> 6;
    const int lane = tid & 63;
    const int bn = blockIdx.x;
    const int bm = blockIdx.y;

    const int wm = (wave >> 1) * 64;        // wave's 64-row band of C
    const int wn = (wave & 1) * 128;        // wave's 128-col band of C

    // staging map: lane l -> LDS slot l*16B = (row l/4, chunk l%4), linear
    const int s_row = lane >> 2;
    const int s_col = (lane & 3) * 8;

    const unsigned short* Ag = A + ((size_t)(bm * BM + wave * 32 + s_row)) * K + s_col;
    const unsigned short* Bg = B + ((size_t)(bn * BN + wave * 64 + s_row)) * K + s_col;
    unsigned short* As_w = &As[(wave * 32) * BK];   // wave-uniform LDS bases
    unsigned short* Bs_w = &Bs[(wave * 64) * BK];

    // reader map (32x32x16 A/B layout: row = lane&31, k = (lane>>5)*8+j)
    const int m   = lane & 31;
    const int cg  = lane >> 5;              // which 8-k half of the 16-k step
    const int p0o = cg * 8;                 // k-step 0: chunks 0,1
    const int p1o = (2 + cg) * 8;           // k-step 1: chunks 2,3

    f32x16 acc[2][4] = {};

    for (int k0 = 0; k0 < K; k0 += BK) {
        __syncthreads();                    // previous iter done reading LDS
        load_lds16(Ag + k0,          As_w);
        load_lds16(Ag + 16 * K + k0, As_w + 16 * BK);
        load_lds16(Bg + k0,          Bs_w);
        load_lds16(Bg + 16 * K + k0, Bs_w + 16 * BK);
        load_lds16(Bg + 32 * K + k0, Bs_w + 32 * BK);
        load_lds16(Bg + 48 * K + k0, Bs_w + 48 * BK);
        __builtin_amdgcn_s_waitcnt(0);      // explicit full drain (safety belt)
        __syncthreads();                    // tiles ready for all waves

        short8 a0[2], a1[2], b0[4], b1[4];
        #pragma unroll
        for (int i = 0; i < 2; ++i) {
            a0[i] = *(const short8*)&As[(wm + i * 32 + m) * BK + p0o];
            a1[i] = *(const short8*)&As[(wm + i * 32 + m) * BK + p1o];
        }
        #pragma unroll
        for (int j = 0; j < 4; ++j) {
            b0[j] = *(const short8*)&Bs[(wn + j * 32 + m) * BK + p0o];
            b1[j] = *(const short8*)&Bs[(wn + j * 32 + m) * BK + p1o];
        }
        #pragma unroll
        for (int i = 0; i < 2; ++i)
            #pragma unroll
            for (int j = 0; j < 4; ++j) {
                acc[i][j] = __builtin_amdgcn_mfma_f32_32x32x16_bf16(
                    a0[i], b0[j], acc[i][j], 0, 0, 0);
                acc[i][j] = __builtin_amdgcn_mfma_f32_32x32x16_bf16(
                    a1[i], b1[j], acc[i][j], 0, 0, 0);
            }
    }

    // epilogue: 32x32 C/D layout col=lane&31, row=(reg&3)+8*(reg>>2)+4*(lane>>5)
    const int cn    = lane & 31;
    const int rbase = 4 * (lane >> 5);
    #pragma unroll
    for (int j = 0; j < 4; ++j) {
        int col = bn * BN + wn + j * 32 + cn;
        float bv = bias[col];
        #pragma unroll
        for (int i = 0; i < 2; ++i) {
            int row0 = bm * BM + wm + i * 32 + rbase;
            #pragma unroll
            for (int reg = 0; reg < 16; ++reg) {
                int row = row0 + (reg & 3) + 8 * (reg >> 2);
                C[(size_t)row * N + col] = acc[i][j][reg] + bv;
            }
        }
    }
}

extern "C" void kernel_launch(void* const* d_in, const int* in_sizes, int n_in,
                              void* d_out, int out_size, void* d_ws, size_t ws_size,
                              hipStream_t stream) {
    const float* x    = (const float*)d_in[0];   // [8192][2048]
    const float* rule = (const float*)d_in[1];   // [4][4][4]
    const float* W    = (const float*)d_in[2];   // [4][512][2048]
    const float* b    = (const float*)d_in[3];   // [8192]
    float* y = (float*)d_out;                    // [8192][8192]

    unsigned short* xb = (unsigned short*)d_ws;                       // 32 MB
    unsigned short* Ht = (unsigned short*)((char*)d_ws +
                         (size_t)TOKENS * IN_FEATS * sizeof(unsigned short)); // 32 MB

    cvt_x_kernel<<<(TOKENS * IN_FEATS) / 8 / 256, 256, 0, stream>>>(x, xb);
    build_ht_kernel<<<dim3(IN_PER / 32, OUT_PER / 64), 256, 0, stream>>>(rule, W, Ht);
    gemm_bt_kernel<<<dim3(OUT_FEATS / BN, TOKENS / BM), 256, 0, stream>>>(xb, Ht, b, y);
}